// Round 2
// baseline (609.657 us; speedup 1.0000x reference)
//
#include <hip/hip_runtime.h>
#include <stdint.h>

typedef unsigned short ushort_t;

#define B_  32
#define D_  4096
#define H1_ 512
#define H2_ 256
#define U_  64

__device__ __forceinline__ float bf2f(ushort_t u) {
    return __uint_as_float(((uint32_t)u) << 16);
}
__device__ __forceinline__ float bflo(uint32_t w) {   // bf16 at even index (low 16 bits)
    return __uint_as_float(w << 16);
}
__device__ __forceinline__ float bfhi(uint32_t w) {   // bf16 at odd index
    return __uint_as_float(w & 0xffff0000u);
}
__device__ __forceinline__ ushort_t f2bfu(float f) {  // RNE float->bf16 bits
    uint32_t x = __float_as_uint(f);
    return (ushort_t)((x + 0x7fffu + ((x >> 16) & 1u)) >> 16);
}

// ---------------------------------------------------------------------------
// K1: the two forward GEMMs (fp32), K-split by 8.
// C[b][n] = sum_k A[b][k] * W[k][n].  grid 256: [gemm(2)][nblk(16)][chunk(8)]
// Thread owns one column n, 32 batch accumulators. A[b][k] is wave-uniform ->
// scalar loads. W loads coalesced dwords.
// partials layout: [gemm][chunk][b][n]  (2*8*32*4096 f32 = 8 MB)
// ---------------------------------------------------------------------------
__global__ __launch_bounds__(256) void k_gemm1(
    const float* __restrict__ stim, const float* __restrict__ prev,
    const float* __restrict__ Wheb, const float* __restrict__ Wrec,
    float* __restrict__ partials)
{
    int bx = blockIdx.x;
    int gemm  = bx >> 7;
    int rem   = bx & 127;
    int nblk  = rem >> 3;
    int chunk = rem & 7;
    const float* A = gemm ? prev : stim;
    const float* W = gemm ? Wrec : Wheb;

    int n  = nblk * 256 + threadIdx.x;
    int k0 = chunk * 512;

    float acc[32];
#pragma unroll
    for (int b = 0; b < 32; b++) acc[b] = 0.f;

    for (int k = k0; k < k0 + 512; k += 2) {
        float w0 = W[(size_t)k * D_ + n];
        float w1 = W[(size_t)(k + 1) * D_ + n];
#pragma unroll
        for (int b = 0; b < 32; b++) {
            float a0 = A[b * D_ + k];       // uniform -> s_load
            float a1 = A[b * D_ + k + 1];
            acc[b] = fmaf(a0, w0, acc[b]);
            acc[b] = fmaf(a1, w1, acc[b]);
        }
    }
    float* P = partials + ((size_t)(gemm * 8 + chunk) * 32) * D_;
#pragma unroll
    for (int b = 0; b < 32; b++) P[b * D_ + n] = acc[b];
}

// ---------------------------------------------------------------------------
// K2: reduce K-split partials, relu, write:
//   outf32 [2][32][4096]  (fp32 row-major relu'd outputs)
//   Tbuf   bf16 sections of 4096*32 u16 each: [0]=ST (stim^T), [1]=PT (prev^T),
//          [2]=OT (stim_out^T), [3]=RT (rec_out^T)
// ---------------------------------------------------------------------------
__global__ __launch_bounds__(256) void k_reduce(
    const float* __restrict__ partials,
    const float* __restrict__ stim, const float* __restrict__ prev,
    float* __restrict__ outf32, ushort_t* __restrict__ Tbuf)
{
    int idx = blockIdx.x * 256 + threadIdx.x;      // 0 .. 262143
    int gemm = idx >> 17;
    int r    = idx & 131071;
    int b    = r >> 12;
    int d    = r & 4095;
    float s = 0.f;
#pragma unroll
    for (int c = 0; c < 8; c++)
        s += partials[((size_t)(gemm * 8 + c) * 32 + b) * D_ + d];
    s = fmaxf(s, 0.f);
    outf32[idx] = s;
    Tbuf[(2 + gemm) * 131072 + d * 32 + b] = f2bfu(s);                 // OT / RT
    Tbuf[gemm * 131072 + d * 32 + b] = f2bfu((gemm ? prev : stim)[r]); // ST / PT
}

// ---------------------------------------------------------------------------
// K3: rec_norm = LN(rec_out) per batch row; final = stim_out + rec_norm.
// Writes final (fp32) to d_out rows 0..31 and to ws for the MLP.
// ---------------------------------------------------------------------------
__global__ __launch_bounds__(256) void k_final_ln(
    const float* __restrict__ outf32,
    const float* __restrict__ g, const float* __restrict__ be,
    float* __restrict__ dout, float* __restrict__ finalf32)
{
    __shared__ float red[256], red2[256];
    int b = blockIdx.x, tid = threadIdx.x;
    const float* rec = outf32 + 131072 + b * D_;
    const float* stm = outf32 + b * D_;

    float s = 0.f, s2 = 0.f;
    for (int d = tid; d < D_; d += 256) { float x = rec[d]; s += x; s2 += x * x; }
    red[tid] = s; red2[tid] = s2; __syncthreads();
    for (int st = 128; st > 0; st >>= 1) {
        if (tid < st) { red[tid] += red[tid + st]; red2[tid] += red2[tid + st]; }
        __syncthreads();
    }
    float m = red[0] * (1.f / D_);
    float v = red2[0] * (1.f / D_) - m * m;
    float rstd = rsqrtf(v + 1e-5f);

    for (int d = tid; d < D_; d += 256) {
        float fn = stm[d] + (rec[d] - m) * rstd * g[d] + be[d];
        finalf32[b * D_ + d] = fn;
        dout[b * D_ + d] = fn;
    }
}

// ---------------------------------------------------------------------------
// K4: fc1 GEMM  z1[b][j] = sum_k final[b][k]*fc1w[k][j], K-split by 64.
// grid 64 = kchunk; thread owns column pair (2t,2t+1), 32 batch accs each.
// z1 partials layout [kc(64)][b(32)][j(512)] f32 = 4 MB
// ---------------------------------------------------------------------------
__global__ __launch_bounds__(256) void k_fc1(
    const float* __restrict__ finalf32, const float* __restrict__ fc1w,
    float* __restrict__ z1p)
{
    int kc = blockIdx.x;
    int t  = threadIdx.x;
    int k0 = kc * 64;
    const float2* W2 = (const float2*)fc1w;

    float a0[32], a1[32];
#pragma unroll
    for (int b = 0; b < 32; b++) { a0[b] = 0.f; a1[b] = 0.f; }

    for (int k = k0; k < k0 + 64; k++) {
        float2 wv = W2[k * (H1_ / 2) + t];
#pragma unroll
        for (int b = 0; b < 32; b++) {
            float a = finalf32[b * D_ + k];        // uniform -> s_load
            a0[b] = fmaf(a, wv.x, a0[b]);
            a1[b] = fmaf(a, wv.y, a1[b]);
        }
    }
    float* P = z1p + (size_t)kc * 32 * H1_;
#pragma unroll
    for (int b = 0; b < 32; b++) {
        P[b * H1_ + 2 * t]     = a0[b];
        P[b * H1_ + 2 * t + 1] = a1[b];
    }
}

// ---------------------------------------------------------------------------
// K5: MLP tail per batch row: reduce z1 + bias, LN+relu, fc2+LN+relu,
// fc3+LN+tanh -> tanhout[b][64]
// ---------------------------------------------------------------------------
__global__ __launch_bounds__(256) void k_tail(
    const float* __restrict__ z1p,
    const float* __restrict__ fc1b,
    const float* __restrict__ ln1g, const float* __restrict__ ln1b,
    const float* __restrict__ fc2w, const float* __restrict__ fc2b,
    const float* __restrict__ ln2g, const float* __restrict__ ln2b,
    const float* __restrict__ fc3w, const float* __restrict__ fc3b,
    const float* __restrict__ lnog, const float* __restrict__ lnob,
    float* __restrict__ tanhout)
{
    __shared__ float sm[512];
    __shared__ float red[256], red2[256];
    __shared__ float h2s[256];
    int b = blockIdx.x, tid = threadIdx.x;

    // ---- z1 reduce + bias
    for (int j = tid; j < H1_; j += 256) {
        float s = fc1b[j];
        for (int c = 0; c < 64; c++)
            s += z1p[((size_t)c * 32 + b) * H1_ + j];
        sm[j] = s;
    }
    __syncthreads();

    // ---- LN over 512
    float s = 0.f, s2 = 0.f;
    for (int j = tid; j < H1_; j += 256) { float x = sm[j]; s += x; s2 += x * x; }
    red[tid] = s; red2[tid] = s2; __syncthreads();
    for (int st = 128; st > 0; st >>= 1) {
        if (tid < st) { red[tid] += red[tid + st]; red2[tid] += red2[tid + st]; }
        __syncthreads();
    }
    float m = red[0] * (1.f / H1_);
    float v = red2[0] * (1.f / H1_) - m * m;
    float rstd = rsqrtf(v + 1e-5f);
    __syncthreads();
    for (int j = tid; j < H1_; j += 256) {
        float h = (sm[j] - m) * rstd * ln1g[j] + ln1b[j];
        sm[j] = fmaxf(h, 0.f);
    }
    __syncthreads();

    // ---- fc2 (thread = output col) + LN over 256 + relu
    float acc = fc2b[tid];
    for (int k = 0; k < H1_; k++)
        acc = fmaf(sm[k], fc2w[k * H2_ + tid], acc);
    red[tid] = acc; red2[tid] = acc * acc; __syncthreads();
    for (int st = 128; st > 0; st >>= 1) {
        if (tid < st) { red[tid] += red[tid + st]; red2[tid] += red2[tid + st]; }
        __syncthreads();
    }
    float m2 = red[0] * (1.f / H2_);
    float v2 = red2[0] * (1.f / H2_) - m2 * m2;
    float rstd2 = rsqrtf(v2 + 1e-5f);
    float h2 = fmaxf((acc - m2) * rstd2 * ln2g[tid] + ln2b[tid], 0.f);
    __syncthreads();
    h2s[tid] = h2; __syncthreads();

    // ---- fc3: j = tid&63, 4-way k-split
    int j  = tid & 63;
    int ks = tid >> 6;
    float p = 0.f;
    for (int kk = 0; kk < 64; kk++) {
        int k = ks * 64 + kk;
        p = fmaf(h2s[k], fc3w[k * U_ + j], p);
    }
    red[tid] = p; __syncthreads();
    if (tid < 64) {
        float x = red[tid] + red[tid + 64] + red[tid + 128] + red[tid + 192]
                + fc3b[tid];
        // LN over 64 via wave butterfly (threads 0..63 = wave 0)
        float ss = x, qq = x * x;
#pragma unroll
        for (int off = 32; off; off >>= 1) {
            ss += __shfl_xor(ss, off, 64);
            qq += __shfl_xor(qq, off, 64);
        }
        float m3 = ss * (1.f / U_);
        float v3 = qq * (1.f / U_) - m3 * m3;
        float to = tanhf((x - m3) * rsqrtf(v3 + 1e-5f) * lnog[tid] + lnob[tid]);
        tanhout[b * U_ + tid] = to;
    }
}

// ---------------------------------------------------------------------------
// K6: weight update + row L2 normalize.
// grid 1024: [mat(2)][itile(512)], 8 rows per block, wave w owns rows 2w,2w+1.
// upd[i][j] = dot32(ST[i][:], OT[j][:]);  v = (W + alpha_j*upd)*(1-decay_i)
// cache bf16 row in LDS (64KB), wave-shfl sumsq reduce, rescale, store fp32.
// alpha[j] is wave-uniform per jt since j/64 == jt.
// ---------------------------------------------------------------------------
__global__ __launch_bounds__(256) void k_update(
    const float* __restrict__ Wheb, const float* __restrict__ Wrec,
    const float* __restrict__ decay, const float* __restrict__ tanhout,
    const ushort_t* __restrict__ Tbuf, float* __restrict__ dout)
{
    __shared__ ushort_t cache[8 * 4096];   // 64 KB
    int bx = blockIdx.x;
    int mat   = bx >> 9;
    int itile = bx & 511;
    int i0    = itile * 8;
    int tid  = threadIdx.x;
    int wv   = tid >> 6;
    int lane = tid & 63;
    int ir0 = i0 + wv * 2, ir1 = ir0 + 1;

    // alpha[lane] = 9.9 * mean_b tanhout[b][lane]   (lane indexes dop)
    float al = 0.f;
#pragma unroll
    for (int b = 0; b < 32; b++) al += tanhout[b * U_ + lane];
    al *= (9.9f / 32.f);

    // preload S^T rows (32 bf16 each) into registers
    const ushort_t* Sp = Tbuf + mat * 131072;
    const uint4* s0p = (const uint4*)(Sp + (size_t)ir0 * 32);
    const uint4* s1p = (const uint4*)(Sp + (size_t)ir1 * 32);
    float st0[32], st1[32];
#pragma unroll
    for (int q = 0; q < 4; q++) {
        uint4 a = s0p[q], c = s1p[q];
        const uint32_t aw[4] = {a.x, a.y, a.z, a.w};
        const uint32_t cw[4] = {c.x, c.y, c.z, c.w};
#pragma unroll
        for (int e = 0; e < 4; e++) {
            st0[q * 8 + 2 * e]     = bflo(aw[e]);
            st0[q * 8 + 2 * e + 1] = bfhi(aw[e]);
            st1[q * 8 + 2 * e]     = bflo(cw[e]);
            st1[q * 8 + 2 * e + 1] = bfhi(cw[e]);
        }
    }
    float dc0 = 1.f - decay[ir0];
    float dc1 = 1.f - decay[ir1];

    const ushort_t* Op = Tbuf + (2 + mat) * 131072;
    const float* Wp = mat ? Wrec : Wheb;

    float ss0 = 0.f, ss1 = 0.f;
    for (int jt = 0; jt < 64; jt++) {
        int j = jt * 64 + lane;
        float av = __shfl(al, jt, 64);
        const uint4* op = (const uint4*)(Op + (size_t)j * 32);
        float u0 = 0.f, u1 = 0.f;
#pragma unroll
        for (int q = 0; q < 4; q++) {
            uint4 a = op[q];
            const uint32_t w4[4] = {a.x, a.y, a.z, a.w};
#pragma unroll
            for (int e = 0; e < 4; e++) {
                float o0 = bflo(w4[e]), o1 = bfhi(w4[e]);
                u0 = fmaf(st0[q * 8 + 2 * e], o0, u0);
                u0 = fmaf(st0[q * 8 + 2 * e + 1], o1, u0);
                u1 = fmaf(st1[q * 8 + 2 * e], o0, u1);
                u1 = fmaf(st1[q * 8 + 2 * e + 1], o1, u1);
            }
        }
        float w0v = Wp[(size_t)ir0 * D_ + j];
        float w1v = Wp[(size_t)ir1 * D_ + j];
        float v0 = (w0v + av * u0) * dc0;
        float v1 = (w1v + av * u1) * dc1;
        ss0 += v0 * v0;
        ss1 += v1 * v1;
        cache[(wv * 2) * 4096 + j]     = f2bfu(v0);
        cache[(wv * 2 + 1) * 4096 + j] = f2bfu(v1);
    }
#pragma unroll
    for (int off = 32; off; off >>= 1) {
        ss0 += __shfl_xor(ss0, off, 64);
        ss1 += __shfl_xor(ss1, off, 64);
    }
    float ri0 = 1.f / fmaxf(sqrtf(ss0), 1e-12f);
    float ri1 = 1.f / fmaxf(sqrtf(ss1), 1e-12f);

    float* O0 = dout + (size_t)(32 + mat * D_ + ir0) * D_;
    float* O1 = O0 + D_;
    for (int j = lane; j < D_; j += 64) {
        O0[j] = bf2f(cache[(wv * 2) * 4096 + j]) * ri0;
        O1[j] = bf2f(cache[(wv * 2 + 1) * 4096 + j]) * ri1;
    }
}

// ---------------------------------------------------------------------------
extern "C" void kernel_launch(void* const* d_in, const int* in_sizes, int n_in,
                              void* d_out, int out_size, void* d_ws, size_t ws_size,
                              hipStream_t stream)
{
    const float* stim = (const float*)d_in[0];
    const float* prev = (const float*)d_in[1];
    const float* Wheb = (const float*)d_in[2];
    const float* Wrec = (const float*)d_in[3];
    const float* decay= (const float*)d_in[4];
    const float* lnrg = (const float*)d_in[5];
    const float* lnrb = (const float*)d_in[6];
    const float* fc1w = (const float*)d_in[7];
    const float* fc1b = (const float*)d_in[8];
    const float* ln1g = (const float*)d_in[9];
    const float* ln1b = (const float*)d_in[10];
    const float* fc2w = (const float*)d_in[11];
    const float* fc2b = (const float*)d_in[12];
    const float* ln2g = (const float*)d_in[13];
    const float* ln2b = (const float*)d_in[14];
    const float* fc3w = (const float*)d_in[15];
    const float* fc3b = (const float*)d_in[16];
    const float* lnog = (const float*)d_in[17];
    const float* lnob = (const float*)d_in[18];

    char* ws = (char*)d_ws;
    float*    P_part  = (float*)(ws + 0);          //  8 MB  [2][8][32][4096]
    float*    P_out   = (float*)(ws + 8388608);    //  1 MB  [2][32][4096]
    ushort_t* P_tbuf  = (ushort_t*)(ws + 9437184); //  1 MB  ST,PT,OT,RT (bf16)
    float*    P_final = (float*)(ws + 10485760);   //  512KB [32][4096]
    float*    P_z1p   = (float*)(ws + 11010048);   //  4 MB  [64][32][512]
    float*    P_tanh  = (float*)(ws + 15204352);   //  8 KB  [32][64]

    float* out = (float*)d_out;

    k_gemm1   <<<256,  256, 0, stream>>>(stim, prev, Wheb, Wrec, P_part);
    k_reduce  <<<1024, 256, 0, stream>>>(P_part, stim, prev, P_out, P_tbuf);
    k_final_ln<<<32,   256, 0, stream>>>(P_out, lnrg, lnrb, out, P_final);
    k_fc1     <<<64,   256, 0, stream>>>(P_final, fc1w, P_z1p);
    k_tail    <<<32,   256, 0, stream>>>(P_z1p, fc1b, ln1g, ln1b, fc2w, fc2b,
                                         ln2g, ln2b, fc3w, fc3b, lnog, lnob, P_tanh);
    k_update  <<<1024, 256, 0, stream>>>(Wheb, Wrec, decay, P_tanh, P_tbuf, out);
}

// Round 3
// 480.712 us; speedup vs baseline: 1.2682x; 1.2682x over previous
//
#include <hip/hip_runtime.h>
#include <stdint.h>

typedef unsigned short ushort_t;
typedef float f32x4 __attribute__((ext_vector_type(4)));
typedef short s16x8 __attribute__((ext_vector_type(8)));

#define B_  32
#define D_  4096
#define H1_ 512
#define H2_ 256
#define U_  64

#define KS_   16        // K-splits for forward GEMM
#define KCH_  256       // K per block (4096/16)
#define NT_   256       // N tile per block
#define APAD  264       // A_lds row stride (u16): 256 + 8 (16B aligned)
#define WPAD  72        // Wt_lds row stride (u16): 64 + 8 (16B aligned)

__device__ __forceinline__ float bf2f(ushort_t u) {
    return __uint_as_float(((uint32_t)u) << 16);
}
__device__ __forceinline__ ushort_t f2bfu(float f) {  // RNE float->bf16 bits
    uint32_t x = __float_as_uint(f);
    return (ushort_t)((x + 0x7fffu + ((x >> 16) & 1u)) >> 16);
}
__device__ __forceinline__ uint32_t pk2bf(float a, float b) {
    return ((uint32_t)f2bfu(a)) | (((uint32_t)f2bfu(b)) << 16);
}

// ---------------------------------------------------------------------------
// K1: forward GEMMs via MFMA 16x16x32 bf16.
// C[b][n] = sum_k A[b][k] * W[k][n], A=[32 x 4096] fp32, W=[4096 x 4096] fp32.
// grid 512: [gemm(2)][nblk(16)][kchunk(16)].  Block: 256 thr = 4 waves.
// Wave w owns n-subtile [w*64, w*64+64): 2 m-tiles x 4 n-tiles of 16x16.
// W tile staged fp32->bf16 TRANSPOSED into LDS (Wt[n][k]) so b-frags are
// contiguous ds_read_b128.  K-split partials -> fp32 atomicAdd into Psum.
// ---------------------------------------------------------------------------
__global__ __launch_bounds__(256, 2) void k_gemm_mfma(
    const float* __restrict__ stim, const float* __restrict__ prev,
    const float* __restrict__ Wheb, const float* __restrict__ Wrec,
    float* __restrict__ Psum)
{
    __shared__ ushort_t Al[32 * APAD];     // 16.9 KB
    __shared__ ushort_t Wt[NT_ * WPAD];    // 36.9 KB

    int bx = blockIdx.x;
    int gemm  = bx >> 8;
    int rem   = bx & 255;
    int nblk  = rem >> 4;
    int chunk = rem & 15;
    const float* A = gemm ? prev : stim;
    const float* W = gemm ? Wrec : Wheb;
    int k0c = chunk * KCH_;
    int n0  = nblk * NT_;
    int tid = threadIdx.x, lane = tid & 63, wave = tid >> 6;
    int col = lane & 15, quad = lane >> 4;

    // ---- stage A [32][256] fp32 -> bf16 LDS (once per block)
#pragma unroll
    for (int p = 0; p < 16; p++) {
        int idx = p * 256 + tid;           // over [32][128] float2
        int b   = idx >> 7;
        int kk  = (idx & 127) * 2;
        float2 v = *(const float2*)(A + (size_t)b * D_ + k0c + kk);
        *(uint32_t*)&Al[b * APAD + kk] = pk2bf(v.x, v.y);
    }

    f32x4 acc[2][4];
#pragma unroll
    for (int mt = 0; mt < 2; mt++)
#pragma unroll
        for (int nt = 0; nt < 4; nt++)
            acc[mt][nt] = (f32x4){0.f, 0.f, 0.f, 0.f};

    // ---- K loop: 4 ksteps of 64
    for (int ks = 0; ks < 4; ks++) {
        __syncthreads();                   // protect Wt before overwrite
        // stage W kstep: thread t = column n0+t, reads 64 strided fp32
        const float* Wc = W + (size_t)(k0c + ks * 64) * D_ + n0 + tid;
        uint32_t* dst = (uint32_t*)&Wt[tid * WPAD];
#pragma unroll
        for (int i = 0; i < 32; i++) {
            float a = Wc[(size_t)(2 * i) * D_];
            float b = Wc[(size_t)(2 * i + 1) * D_];
            dst[i] = pk2bf(a, b);
        }
        __syncthreads();

#pragma unroll
        for (int kq = 0; kq < 2; kq++) {
            int kb = ks * 64 + kq * 32 + quad * 8;   // k in A_lds chunk
            int kw = kq * 32 + quad * 8;             // k in Wt row
            s16x8 af[2], bf[4];
            af[0] = *(const s16x8*)&Al[col * APAD + kb];
            af[1] = *(const s16x8*)&Al[(col + 16) * APAD + kb];
#pragma unroll
            for (int nt = 0; nt < 4; nt++)
                bf[nt] = *(const s16x8*)&Wt[(wave * 64 + nt * 16 + col) * WPAD + kw];
#pragma unroll
            for (int mt = 0; mt < 2; mt++)
#pragma unroll
                for (int nt = 0; nt < 4; nt++)
                    acc[mt][nt] = __builtin_amdgcn_mfma_f32_16x16x32_bf16(
                        af[mt], bf[nt], acc[mt][nt], 0, 0, 0);
        }
    }

    // ---- epilogue: atomic accumulate K-split partials
    float* P = Psum + (size_t)gemm * 32 * D_;
#pragma unroll
    for (int mt = 0; mt < 2; mt++)
#pragma unroll
        for (int nt = 0; nt < 4; nt++)
#pragma unroll
            for (int r = 0; r < 4; r++) {
                int b = mt * 16 + quad * 4 + r;
                int n = n0 + wave * 64 + nt * 16 + col;
                atomicAdd(&P[(size_t)b * D_ + n], acc[mt][nt][r]);
            }
}

// ---------------------------------------------------------------------------
// K2: relu Psum -> P_relu (fp32) + build bf16 transposed copies:
//   Tbuf sections of 4096*32 u16: [0]=ST (stim^T), [1]=PT (prev^T),
//        [2]=OT (stim_out^T), [3]=RT (rec_out^T)
// ---------------------------------------------------------------------------
__global__ __launch_bounds__(256) void k_reduce(
    const float* __restrict__ Psum,
    const float* __restrict__ stim, const float* __restrict__ prev,
    float* __restrict__ P_relu, ushort_t* __restrict__ Tbuf)
{
    int idx = blockIdx.x * 256 + threadIdx.x;      // 0 .. 262143
    int gemm = idx >> 17;
    int r    = idx & 131071;
    int b    = r >> 12;
    int d    = r & 4095;
    float s = fmaxf(Psum[idx], 0.f);
    P_relu[idx] = s;
    Tbuf[(2 + gemm) * 131072 + d * 32 + b] = f2bfu(s);                 // OT / RT
    Tbuf[gemm * 131072 + d * 32 + b] = f2bfu((gemm ? prev : stim)[r]); // ST / PT
}

// ---------------------------------------------------------------------------
// K3: rec_norm = LN(rec_out) per batch row; final = stim_out + rec_norm.
// ---------------------------------------------------------------------------
__global__ __launch_bounds__(256) void k_final_ln(
    const float* __restrict__ P_relu,
    const float* __restrict__ g, const float* __restrict__ be,
    float* __restrict__ dout, float* __restrict__ finalf32)
{
    __shared__ float red[256], red2[256];
    int b = blockIdx.x, tid = threadIdx.x;
    const float* rec = P_relu + 131072 + b * D_;
    const float* stm = P_relu + b * D_;

    float s = 0.f, s2 = 0.f;
    for (int d = tid; d < D_; d += 256) { float x = rec[d]; s += x; s2 += x * x; }
    red[tid] = s; red2[tid] = s2; __syncthreads();
    for (int st = 128; st > 0; st >>= 1) {
        if (tid < st) { red[tid] += red[tid + st]; red2[tid] += red2[tid + st]; }
        __syncthreads();
    }
    float m = red[0] * (1.f / D_);
    float v = red2[0] * (1.f / D_) - m * m;
    float rstd = rsqrtf(v + 1e-5f);

    for (int d = tid; d < D_; d += 256) {
        float fn = stm[d] + (rec[d] - m) * rstd * g[d] + be[d];
        finalf32[b * D_ + d] = fn;
        dout[b * D_ + d] = fn;
    }
}

// ---------------------------------------------------------------------------
// K4: fc1 GEMM  z1[b][j] = sum_k final[b][k]*fc1w[k][j], K-split by 64.
// ---------------------------------------------------------------------------
__global__ __launch_bounds__(256) void k_fc1(
    const float* __restrict__ finalf32, const float* __restrict__ fc1w,
    float* __restrict__ z1p)
{
    int kc = blockIdx.x;
    int t  = threadIdx.x;
    int k0 = kc * 64;
    const float2* W2 = (const float2*)fc1w;

    float a0[32], a1[32];
#pragma unroll
    for (int b = 0; b < 32; b++) { a0[b] = 0.f; a1[b] = 0.f; }

    for (int k = k0; k < k0 + 64; k++) {
        float2 wv = W2[k * (H1_ / 2) + t];
#pragma unroll
        for (int b = 0; b < 32; b++) {
            float a = finalf32[b * D_ + k];        // uniform -> s_load
            a0[b] = fmaf(a, wv.x, a0[b]);
            a1[b] = fmaf(a, wv.y, a1[b]);
        }
    }
    float* P = z1p + (size_t)kc * 32 * H1_;
#pragma unroll
    for (int b = 0; b < 32; b++) {
        P[b * H1_ + 2 * t]     = a0[b];
        P[b * H1_ + 2 * t + 1] = a1[b];
    }
}

// ---------------------------------------------------------------------------
// K5: MLP tail per batch row.
// ---------------------------------------------------------------------------
__global__ __launch_bounds__(256) void k_tail(
    const float* __restrict__ z1p,
    const float* __restrict__ fc1b,
    const float* __restrict__ ln1g, const float* __restrict__ ln1b,
    const float* __restrict__ fc2w, const float* __restrict__ fc2b,
    const float* __restrict__ ln2g, const float* __restrict__ ln2b,
    const float* __restrict__ fc3w, const float* __restrict__ fc3b,
    const float* __restrict__ lnog, const float* __restrict__ lnob,
    float* __restrict__ tanhout)
{
    __shared__ float sm[512];
    __shared__ float red[256], red2[256];
    __shared__ float h2s[256];
    int b = blockIdx.x, tid = threadIdx.x;

    for (int j = tid; j < H1_; j += 256) {
        float s = fc1b[j];
        for (int c = 0; c < 64; c++)
            s += z1p[((size_t)c * 32 + b) * H1_ + j];
        sm[j] = s;
    }
    __syncthreads();

    float s = 0.f, s2 = 0.f;
    for (int j = tid; j < H1_; j += 256) { float x = sm[j]; s += x; s2 += x * x; }
    red[tid] = s; red2[tid] = s2; __syncthreads();
    for (int st = 128; st > 0; st >>= 1) {
        if (tid < st) { red[tid] += red[tid + st]; red2[tid] += red2[tid + st]; }
        __syncthreads();
    }
    float m = red[0] * (1.f / H1_);
    float v = red2[0] * (1.f / H1_) - m * m;
    float rstd = rsqrtf(v + 1e-5f);
    __syncthreads();
    for (int j = tid; j < H1_; j += 256) {
        float h = (sm[j] - m) * rstd * ln1g[j] + ln1b[j];
        sm[j] = fmaxf(h, 0.f);
    }
    __syncthreads();

    float acc = fc2b[tid];
    for (int k = 0; k < H1_; k++)
        acc = fmaf(sm[k], fc2w[k * H2_ + tid], acc);
    red[tid] = acc; red2[tid] = acc * acc; __syncthreads();
    for (int st = 128; st > 0; st >>= 1) {
        if (tid < st) { red[tid] += red[tid + st]; red2[tid] += red2[tid + st]; }
        __syncthreads();
    }
    float m2 = red[0] * (1.f / H2_);
    float v2 = red2[0] * (1.f / H2_) - m2 * m2;
    float rstd2 = rsqrtf(v2 + 1e-5f);
    float h2 = fmaxf((acc - m2) * rstd2 * ln2g[tid] + ln2b[tid], 0.f);
    __syncthreads();
    h2s[tid] = h2; __syncthreads();

    int j  = tid & 63;
    int ks = tid >> 6;
    float p = 0.f;
    for (int kk = 0; kk < 64; kk++) {
        int k = ks * 64 + kk;
        p = fmaf(h2s[k], fc3w[k * U_ + j], p);
    }
    red[tid] = p; __syncthreads();
    if (tid < 64) {
        float x = red[tid] + red[tid + 64] + red[tid + 128] + red[tid + 192]
                + fc3b[tid];
        float ss = x, qq = x * x;
#pragma unroll
        for (int off = 32; off; off >>= 1) {
            ss += __shfl_xor(ss, off, 64);
            qq += __shfl_xor(qq, off, 64);
        }
        float m3 = ss * (1.f / U_);
        float v3 = qq * (1.f / U_) - m3 * m3;
        float to = tanhf((x - m3) * rsqrtf(v3 + 1e-5f) * lnog[tid] + lnob[tid]);
        tanhout[b * U_ + tid] = to;
    }
}

// ---------------------------------------------------------------------------
// K6: weight update + row L2 normalize (unchanged from R2).
// ---------------------------------------------------------------------------
__global__ __launch_bounds__(256) void k_update(
    const float* __restrict__ Wheb, const float* __restrict__ Wrec,
    const float* __restrict__ decay, const float* __restrict__ tanhout,
    const ushort_t* __restrict__ Tbuf, float* __restrict__ dout)
{
    __shared__ ushort_t cache[8 * 4096];   // 64 KB
    int bx = blockIdx.x;
    int mat   = bx >> 9;
    int itile = bx & 511;
    int i0    = itile * 8;
    int tid  = threadIdx.x;
    int wv   = tid >> 6;
    int lane = tid & 63;
    int ir0 = i0 + wv * 2, ir1 = ir0 + 1;

    float al = 0.f;
#pragma unroll
    for (int b = 0; b < 32; b++) al += tanhout[b * U_ + lane];
    al *= (9.9f / 32.f);

    const ushort_t* Sp = Tbuf + mat * 131072;
    const uint4* s0p = (const uint4*)(Sp + (size_t)ir0 * 32);
    const uint4* s1p = (const uint4*)(Sp + (size_t)ir1 * 32);
    float st0[32], st1[32];
#pragma unroll
    for (int q = 0; q < 4; q++) {
        uint4 a = s0p[q], c = s1p[q];
        const uint32_t aw[4] = {a.x, a.y, a.z, a.w};
        const uint32_t cw[4] = {c.x, c.y, c.z, c.w};
#pragma unroll
        for (int e = 0; e < 4; e++) {
            st0[q * 8 + 2 * e]     = __uint_as_float(aw[e] << 16);
            st0[q * 8 + 2 * e + 1] = __uint_as_float(aw[e] & 0xffff0000u);
            st1[q * 8 + 2 * e]     = __uint_as_float(cw[e] << 16);
            st1[q * 8 + 2 * e + 1] = __uint_as_float(cw[e] & 0xffff0000u);
        }
    }
    float dc0 = 1.f - decay[ir0];
    float dc1 = 1.f - decay[ir1];

    const ushort_t* Op = Tbuf + (2 + mat) * 131072;
    const float* Wp = mat ? Wrec : Wheb;

    float ss0 = 0.f, ss1 = 0.f;
    for (int jt = 0; jt < 64; jt++) {
        int j = jt * 64 + lane;
        float av = __shfl(al, jt, 64);
        const uint4* op = (const uint4*)(Op + (size_t)j * 32);
        float u0 = 0.f, u1 = 0.f;
#pragma unroll
        for (int q = 0; q < 4; q++) {
            uint4 a = op[q];
            const uint32_t w4[4] = {a.x, a.y, a.z, a.w};
#pragma unroll
            for (int e = 0; e < 4; e++) {
                float o0 = __uint_as_float(w4[e] << 16);
                float o1 = __uint_as_float(w4[e] & 0xffff0000u);
                u0 = fmaf(st0[q * 8 + 2 * e], o0, u0);
                u0 = fmaf(st0[q * 8 + 2 * e + 1], o1, u0);
                u1 = fmaf(st1[q * 8 + 2 * e], o0, u1);
                u1 = fmaf(st1[q * 8 + 2 * e + 1], o1, u1);
            }
        }
        float w0v = Wp[(size_t)ir0 * D_ + j];
        float w1v = Wp[(size_t)ir1 * D_ + j];
        float v0 = (w0v + av * u0) * dc0;
        float v1 = (w1v + av * u1) * dc1;
        ss0 += v0 * v0;
        ss1 += v1 * v1;
        cache[(wv * 2) * 4096 + j]     = f2bfu(v0);
        cache[(wv * 2 + 1) * 4096 + j] = f2bfu(v1);
    }
#pragma unroll
    for (int off = 32; off; off >>= 1) {
        ss0 += __shfl_xor(ss0, off, 64);
        ss1 += __shfl_xor(ss1, off, 64);
    }
    float ri0 = 1.f / fmaxf(sqrtf(ss0), 1e-12f);
    float ri1 = 1.f / fmaxf(sqrtf(ss1), 1e-12f);

    float* O0 = dout + (size_t)(32 + mat * D_ + ir0) * D_;
    float* O1 = O0 + D_;
    for (int j = lane; j < D_; j += 64) {
        O0[j] = bf2f(cache[(wv * 2) * 4096 + j]) * ri0;
        O1[j] = bf2f(cache[(wv * 2 + 1) * 4096 + j]) * ri1;
    }
}

// ---------------------------------------------------------------------------
extern "C" void kernel_launch(void* const* d_in, const int* in_sizes, int n_in,
                              void* d_out, int out_size, void* d_ws, size_t ws_size,
                              hipStream_t stream)
{
    const float* stim = (const float*)d_in[0];
    const float* prev = (const float*)d_in[1];
    const float* Wheb = (const float*)d_in[2];
    const float* Wrec = (const float*)d_in[3];
    const float* decay= (const float*)d_in[4];
    const float* lnrg = (const float*)d_in[5];
    const float* lnrb = (const float*)d_in[6];
    const float* fc1w = (const float*)d_in[7];
    const float* fc1b = (const float*)d_in[8];
    const float* ln1g = (const float*)d_in[9];
    const float* ln1b = (const float*)d_in[10];
    const float* fc2w = (const float*)d_in[11];
    const float* fc2b = (const float*)d_in[12];
    const float* ln2g = (const float*)d_in[13];
    const float* ln2b = (const float*)d_in[14];
    const float* fc3w = (const float*)d_in[15];
    const float* fc3b = (const float*)d_in[16];
    const float* lnog = (const float*)d_in[17];
    const float* lnob = (const float*)d_in[18];

    char* ws = (char*)d_ws;
    float*    P_sum   = (float*)(ws + 0);          // 1 MB   [2][32][4096]
    float*    P_relu  = (float*)(ws + 1048576);    // 1 MB   [2][32][4096]
    ushort_t* P_tbuf  = (ushort_t*)(ws + 2097152); // 1 MB   ST,PT,OT,RT (bf16)
    float*    P_final = (float*)(ws + 3145728);    // 512 KB [32][4096]
    float*    P_z1p   = (float*)(ws + 3670016);    // 4 MB   [64][32][512]
    float*    P_tanh  = (float*)(ws + 7864320);    // 8 KB   [32][64]

    float* out = (float*)d_out;

    hipMemsetAsync(P_sum, 0, 2 * 32 * D_ * sizeof(float), stream);

    k_gemm_mfma<<<512,  256, 0, stream>>>(stim, prev, Wheb, Wrec, P_sum);
    k_reduce   <<<1024, 256, 0, stream>>>(P_sum, stim, prev, P_relu, P_tbuf);
    k_final_ln <<<32,   256, 0, stream>>>(P_relu, lnrg, lnrb, out, P_final);
    k_fc1      <<<64,   256, 0, stream>>>(P_final, fc1w, P_z1p);
    k_tail     <<<32,   256, 0, stream>>>(P_z1p, fc1b, ln1g, ln1b, fc2w, fc2b,
                                          ln2g, ln2b, fc3w, fc3b, lnog, lnob, P_tanh);
    k_update   <<<1024, 256, 0, stream>>>(Wheb, Wrec, decay, P_tanh, P_tbuf, out);
}